// Round 1
// baseline (1087.188 us; speedup 1.0000x reference)
//
#include <hip/hip_runtime.h>
#include <cstdio>

#define NB 40
#define NS 8
#define NT 441
#define DIN 768
#define DD 128
#define NTOT (NB*NT)
#define FSCALE 0.08838834764831843f

struct PP {
  const float *inputs; const int *tok_idx; const float *abs_grid;
  const float *slots_init, *Sp_init, *Ss_init;
  const float *WQ, *ln_g, *ln_b;
  const float *gru_w_ih, *gru_w_hh, *gru_b_ih, *gru_b_hh;
  const float *mlp_ln_g, *mlp_ln_b, *mlp_w1, *mlp_b1, *mlp_w2, *mlp_b2;
  const float *WK, *WV, *Wg, *bg, *Wf1, *bf1, *Wf2, *bf2;
  const float *im_ln1_g, *im_ln1_b, *im_w1, *im_b1, *im_w2, *im_b2, *im_ln2_g, *im_ln2_b;
  const float *fin_w, *fin_b;
  float *x, *A_K, *A_V, *ag, *WKf, *WVf, *Wg1, *c1, *Wf2T;
  float *slots, *Sp0, *Sp1, *Ss0, *Ss1, *qW, *qb, *dots, *attn;
  float *hbar_part, *Sp_part, *hbar;
  float *out;
};

// ---------- weight prep: WKf=WK@Wf1, WVf=WV@Wf1, Wg1=Wg@Wf1, c1=bg@Wf1+bf1, Wf2T ----------
__global__ __launch_bounds__(128) void prep_weights(PP p){
  int r = blockIdx.x, d = threadIdx.x;
  float accK = 0.f, accV = 0.f;
  for (int kk = 0; kk < DD; kk++){
    float w = p.Wf1[kk*DD + d];
    accK = fmaf(p.WK[r*DD+kk], w, accK);
    accV = fmaf(p.WV[r*DD+kk], w, accV);
  }
  p.WKf[r*DD+d] = accK; p.WVf[r*DD+d] = accV;
  if (r < 2){
    float a = 0.f;
    for (int kk = 0; kk < DD; kk++) a = fmaf(p.Wg[r*DD+kk], p.Wf1[kk*DD+d], a);
    p.Wg1[r*DD+d] = a;
  }
  if (r == 2){
    float a = 0.f;
    for (int kk = 0; kk < DD; kk++) a = fmaf(p.bg[kk], p.Wf1[kk*DD+d], a);
    p.c1[d] = a + p.bf1[d];
  }
  // Wf2T[d][r] = Wf2[r][d]
  p.Wf2T[d*DD + r] = p.Wf2[r*DD + d];
}

// ---------- state init ----------
__global__ void init_state(PP p){
  int i = blockIdx.x*256 + threadIdx.x;
  if (i < NB*NS*DD) p.slots[i] = p.slots_init[i & (NS*DD-1)];
  if (i < NB*NS*2){
    p.Sp0[i] = p.Sp_init[i & (NS*2-1)];
    p.Ss0[i] = p.Ss_init[i & (NS*2-1)];
  }
}

// ---------- gather abs_grid per token ----------
__global__ void gather_ag(PP p){
  int i = blockIdx.x*256 + threadIdx.x;
  if (i < NTOT){
    int idx = p.tok_idx[i];
    p.ag[i*2+0] = p.abs_grid[idx*2+0];
    p.ag[i*2+1] = p.abs_grid[idx*2+1];
  }
}

// ---------- fused initial MLP: x = LN2(relu(LN1(in)@W1+b1)@W2+b2) ----------
__global__ __launch_bounds__(256) void k1_initial_mlp(PP p){
  __shared__ float xn[16][772];   // 49408 B
  __shared__ float hb[16][132];   // 8448 B
  int tid = threadIdx.x;
  int g0 = blockIdx.x * 16;
  // cooperative load
  for (int f = tid; f < 16*192; f += 256){
    int tok = f / 192, pos = (f % 192) * 4;
    int gt = g0 + tok;
    float4 v = (gt < NTOT) ? *(const float4*)(p.inputs + (long)gt*DIN + pos)
                           : make_float4(0.f,0.f,0.f,0.f);
    *(float4*)&xn[tok][pos] = v;
  }
  __syncthreads();
  // LN1: 16 threads per token
  {
    int tok = tid >> 4, l = tid & 15;
    float s = 0.f, s2 = 0.f;
    for (int i = l; i < DIN; i += 16){ float v = xn[tok][i]; s += v; s2 += v*v; }
    for (int m = 1; m < 16; m <<= 1){ s += __shfl_xor(s, m, 16); s2 += __shfl_xor(s2, m, 16); }
    float mean = s*(1.f/DIN), var = s2*(1.f/DIN) - mean*mean;
    float rstd = rsqrtf(var + 1e-5f);
    for (int i = l; i < DIN; i += 16){
      float v = xn[tok][i];
      xn[tok][i] = (v-mean)*rstd*p.im_ln1_g[i] + p.im_ln1_b[i];
    }
  }
  __syncthreads();
  int hc = tid & 127, th = tid >> 7;    // th: token group (0..1), 8 tokens each
  float acc[8];
  #pragma unroll
  for (int t8 = 0; t8 < 8; t8++) acc[t8] = 0.f;
  for (int c = 0; c < 6; c++){
    float hreg[8];
    #pragma unroll
    for (int t8 = 0; t8 < 8; t8++) hreg[t8] = p.im_b1[c*128+hc];
    for (int kk = 0; kk < DIN; kk += 4){
      float w0 = p.im_w1[(long)(kk+0)*DIN + c*128+hc];
      float w1 = p.im_w1[(long)(kk+1)*DIN + c*128+hc];
      float w2 = p.im_w1[(long)(kk+2)*DIN + c*128+hc];
      float w3 = p.im_w1[(long)(kk+3)*DIN + c*128+hc];
      #pragma unroll
      for (int t8 = 0; t8 < 8; t8++){
        int tok = th*8 + t8;
        float4 xv = *(const float4*)&xn[tok][kk];
        hreg[t8] = fmaf(xv.x,w0, fmaf(xv.y,w1, fmaf(xv.z,w2, fmaf(xv.w,w3, hreg[t8]))));
      }
    }
    __syncthreads();   // previous layer-2 reads done before overwrite
    #pragma unroll
    for (int t8 = 0; t8 < 8; t8++) hb[th*8+t8][hc] = fmaxf(hreg[t8], 0.f);
    __syncthreads();
    for (int kk = 0; kk < 128; kk += 4){
      float w0 = p.im_w2[(long)(c*128+kk+0)*DD + hc];
      float w1 = p.im_w2[(long)(c*128+kk+1)*DD + hc];
      float w2 = p.im_w2[(long)(c*128+kk+2)*DD + hc];
      float w3 = p.im_w2[(long)(c*128+kk+3)*DD + hc];
      #pragma unroll
      for (int t8 = 0; t8 < 8; t8++){
        int tok = th*8 + t8;
        float4 hv = *(const float4*)&hb[tok][kk];
        acc[t8] = fmaf(hv.x,w0, fmaf(hv.y,w1, fmaf(hv.z,w2, fmaf(hv.w,w3, acc[t8]))));
      }
    }
    __syncthreads();
  }
  #pragma unroll
  for (int t8 = 0; t8 < 8; t8++) hb[th*8+t8][hc] = acc[t8] + p.im_b2[hc];
  __syncthreads();
  // LN2 + write
  {
    int tok = tid >> 4, l = tid & 15;
    float s = 0.f, s2 = 0.f;
    for (int i = l; i < DD; i += 16){ float v = hb[tok][i]; s += v; s2 += v*v; }
    for (int m = 1; m < 16; m <<= 1){ s += __shfl_xor(s, m, 16); s2 += __shfl_xor(s2, m, 16); }
    float mean = s*(1.f/DD), var = s2*(1.f/DD) - mean*mean;
    float rstd = rsqrtf(var + 1e-5f);
    int gt = g0 + tok;
    if (gt < NTOT)
      for (int i = l; i < DD; i += 16)
        p.x[(long)gt*DD + i] = (hb[tok][i]-mean)*rstd*p.im_ln2_g[i] + p.im_ln2_b[i];
  }
}

// ---------- A_K = x@WKf + c1 ; A_V = x@WVf + c1 ----------
__global__ __launch_bounds__(256) void k2_proj(PP p){
  __shared__ float xt[32][132];
  int tid = threadIdx.x; int g0 = blockIdx.x * 32;
  for (int f = tid; f < 32*32; f += 256){
    int tok = f >> 5, pos = (f & 31) * 4;
    int gt = g0 + tok;
    float4 v = (gt < NTOT) ? *(const float4*)(p.x + (long)gt*DD + pos)
                           : make_float4(0.f,0.f,0.f,0.f);
    *(float4*)&xt[tok][pos] = v;
  }
  __syncthreads();
  int d = tid & 127, grp = tid >> 7;
  float aK[16], aV[16];
  float c1v = p.c1[d];
  #pragma unroll
  for (int t = 0; t < 16; t++){ aK[t] = c1v; aV[t] = c1v; }
  for (int kk = 0; kk < DD; kk += 4){
    float k0 = p.WKf[(kk+0)*DD+d], k1 = p.WKf[(kk+1)*DD+d], k2 = p.WKf[(kk+2)*DD+d], k3 = p.WKf[(kk+3)*DD+d];
    float v0 = p.WVf[(kk+0)*DD+d], v1 = p.WVf[(kk+1)*DD+d], v2 = p.WVf[(kk+2)*DD+d], v3 = p.WVf[(kk+3)*DD+d];
    #pragma unroll
    for (int t = 0; t < 16; t++){
      float4 xv = *(const float4*)&xt[grp*16+t][kk];
      aK[t] = fmaf(xv.x,k0, fmaf(xv.y,k1, fmaf(xv.z,k2, fmaf(xv.w,k3, aK[t]))));
      aV[t] = fmaf(xv.x,v0, fmaf(xv.y,v1, fmaf(xv.z,v2, fmaf(xv.w,v3, aV[t]))));
    }
  }
  #pragma unroll
  for (int t = 0; t < 16; t++){
    int gt = g0 + grp*16 + t;
    if (gt < NTOT){ p.A_K[(long)gt*DD+d] = aK[t]; p.A_V[(long)gt*DD+d] = aV[t]; }
  }
}

// ---------- per-(b,s): sn=LN(slots), q=sn@WQ, qW=Wf2@q (via Wf2T), qb=SCALE*(bf2.q) ----------
__global__ __launch_bounds__(128) void k3_slots(PP p){
  int bs = blockIdx.x, d = threadIdx.x;
  __shared__ float sn[128], q[128];
  __shared__ float rs[2][2];
  float v = p.slots[bs*DD+d];
  float s = v, s2 = v*v;
  for (int m = 1; m < 64; m <<= 1){ s += __shfl_xor(s, m); s2 += __shfl_xor(s2, m); }
  if ((d & 63) == 0){ rs[d>>6][0] = s; rs[d>>6][1] = s2; }
  __syncthreads();
  s = rs[0][0] + rs[1][0]; s2 = rs[0][1] + rs[1][1];
  float mean = s*(1.f/DD), var = s2*(1.f/DD) - mean*mean, rstd = rsqrtf(var + 1e-5f);
  sn[d] = (v-mean)*rstd*p.ln_g[d] + p.ln_b[d];
  __syncthreads();
  float acc = 0.f;
  for (int kk = 0; kk < DD; kk++) acc = fmaf(sn[kk], p.WQ[kk*DD+d], acc);
  q[d] = acc;
  __syncthreads();
  float a2 = 0.f;
  for (int dd = 0; dd < DD; dd++) a2 = fmaf(q[dd], p.Wf2T[dd*DD+d], a2);
  p.qW[bs*DD+d] = a2;
  float pb = p.bf2[d]*q[d];
  for (int m = 1; m < 64; m <<= 1) pb += __shfl_xor(pb, m);
  if ((d & 63) == 0) rs[d>>6][0] = pb;
  __syncthreads();
  if (d == 0) p.qb[bs] = (rs[0][0] + rs[1][0]) * FSCALE;
}

// ---------- dots[b,s,j] = SCALE * (sum_d relu(A_K + rel@Wg1) * qW) + qb ----------
__global__ __launch_bounds__(256) void k4_dots(PP p, const float* Sp, const float* Ss){
  int b = blockIdx.x / 7, tile = blockIdx.x % 7;
  int tid = threadIdx.x, wid = tid >> 6, lane = tid & 63;
  int tl = lane >> 2, dg = lane & 3;
  __shared__ float qws[8][132];   // swizzled: [s][(d&31)*4 + (d>>5)]
  __shared__ float spss[8][4];
  __shared__ float qbs[8];
  for (int f = tid; f < 8*128; f += 256){
    int s = f >> 7, d = f & 127;
    qws[s][(d&31)*4 + (d>>5)] = p.qW[(b*NS+s)*DD+d];
  }
  if (tid < 8) qbs[tid] = p.qb[b*NS+tid];
  if (tid < 32){
    int s = tid >> 2, c = tid & 3;
    spss[s][c] = (c < 2) ? Sp[(b*NS+s)*2+c] : 1.f/(Ss[(b*NS+s)*2+(c-2)]*5.0f);
  }
  __syncthreads();
  int j = tile*64 + wid*16 + tl;
  bool valid = j < NT;
  int jj = valid ? j : 0;
  float aa[32], w0[32], w1[32];
  {
    const float* src = p.A_K + ((long)(b*NT+jj))*DD + dg*32;
    #pragma unroll
    for (int i4 = 0; i4 < 8; i4++){
      float4 t = *(const float4*)(src + i4*4);
      aa[i4*4+0]=t.x; aa[i4*4+1]=t.y; aa[i4*4+2]=t.z; aa[i4*4+3]=t.w;
    }
    #pragma unroll
    for (int i4 = 0; i4 < 8; i4++){
      float4 t0 = *(const float4*)(p.Wg1 + dg*32 + i4*4);
      float4 t1 = *(const float4*)(p.Wg1 + DD + dg*32 + i4*4);
      w0[i4*4+0]=t0.x; w0[i4*4+1]=t0.y; w0[i4*4+2]=t0.z; w0[i4*4+3]=t0.w;
      w1[i4*4+0]=t1.x; w1[i4*4+1]=t1.y; w1[i4*4+2]=t1.z; w1[i4*4+3]=t1.w;
    }
  }
  float ag0 = p.ag[(b*NT+jj)*2], ag1 = p.ag[(b*NT+jj)*2+1];
  #pragma unroll
  for (int s = 0; s < 8; s++){
    float rel0 = (ag0 - spss[s][0])*spss[s][2];
    float rel1 = (ag1 - spss[s][1])*spss[s][3];
    float acc = 0.f;
    #pragma unroll
    for (int i = 0; i < 32; i++){
      float hk = fmaxf(fmaf(rel0, w0[i], fmaf(rel1, w1[i], aa[i])), 0.f);
      acc = fmaf(hk, qws[s][i*4+dg], acc);
    }
    acc += __shfl_xor(acc, 1); acc += __shfl_xor(acc, 2);
    if (dg == 0 && valid) p.dots[(b*NS+s)*NT + j] = acc*FSCALE + qbs[s];
  }
}

// ---------- softmax over s, +eps, renormalize over j ----------
__global__ __launch_bounds__(256) void k5_softmax(PP p){
  int b = blockIdx.x, tid = threadIdx.x;
  float a0[8], a1[8];
  float psum[8];
  #pragma unroll
  for (int s = 0; s < 8; s++) psum[s] = 0.f;
  bool has1 = (tid + 256) < NT;
  {
    int j = tid;
    float dv[8]; float m = -1e30f;
    #pragma unroll
    for (int s = 0; s < 8; s++){ dv[s] = p.dots[(b*NS+s)*NT+j]; m = fmaxf(m, dv[s]); }
    float tot = 0.f;
    #pragma unroll
    for (int s = 0; s < 8; s++){ dv[s] = expf(dv[s]-m); tot += dv[s]; }
    float inv = 1.f/tot;
    #pragma unroll
    for (int s = 0; s < 8; s++){ a0[s] = dv[s]*inv + 1e-8f; psum[s] += a0[s]; }
  }
  if (has1){
    int j = tid + 256;
    float dv[8]; float m = -1e30f;
    #pragma unroll
    for (int s = 0; s < 8; s++){ dv[s] = p.dots[(b*NS+s)*NT+j]; m = fmaxf(m, dv[s]); }
    float tot = 0.f;
    #pragma unroll
    for (int s = 0; s < 8; s++){ dv[s] = expf(dv[s]-m); tot += dv[s]; }
    float inv = 1.f/tot;
    #pragma unroll
    for (int s = 0; s < 8; s++){ a1[s] = dv[s]*inv + 1e-8f; psum[s] += a1[s]; }
  }
  #pragma unroll
  for (int s = 0; s < 8; s++)
    for (int m2 = 1; m2 < 64; m2 <<= 1) psum[s] += __shfl_xor(psum[s], m2);
  __shared__ float wsum[4][8];
  __shared__ float sums[8];
  if ((tid & 63) == 0)
    for (int s = 0; s < 8; s++) wsum[tid>>6][s] = psum[s];
  __syncthreads();
  if (tid < 8) sums[tid] = wsum[0][tid]+wsum[1][tid]+wsum[2][tid]+wsum[3][tid];
  __syncthreads();
  {
    int j = tid;
    #pragma unroll
    for (int s = 0; s < 8; s++) p.attn[(b*NS+s)*NT+j] = a0[s]/sums[s];
  }
  if (has1){
    int j = tid + 256;
    #pragma unroll
    for (int s = 0; s < 8; s++) p.attn[(b*NS+s)*NT+j] = a1[s]/sums[s];
  }
}

// ---------- hbar partials (sum_j attn*relu(A_V+rel@Wg1)) and S_p partials ----------
__global__ __launch_bounds__(256) void k6a(PP p, const float* Sp, const float* Ss){
  int b = blockIdx.x >> 3, tile = blockIdx.x & 7;
  int tid = threadIdx.x, wid = tid >> 6, lane = tid & 63;
  int j0 = tile*56; int jn = min(NT, j0+56) - j0;
  __shared__ float atile[8][56];
  __shared__ float spss[8][4];
  __shared__ float hpart[4][8][128];
  __shared__ float ppart[4][8][2];
  for (int f = tid; f < 8*56; f += 256){
    int s = f/56, jj = f%56;
    atile[s][jj] = (j0+jj < NT) ? p.attn[(b*NS+s)*NT + j0+jj] : 0.f;
  }
  if (tid < 32){
    int s = tid >> 2, c = tid & 3;
    spss[s][c] = (c < 2) ? Sp[(b*NS+s)*2+c] : 1.f/(Ss[(b*NS+s)*2+(c-2)]*5.0f);
  }
  __syncthreads();
  int d0 = lane, d1 = lane + 64;
  float wg00 = p.Wg1[d0], wg10 = p.Wg1[DD+d0], wg01 = p.Wg1[d1], wg11 = p.Wg1[DD+d1];
  float acc0[8], acc1[8], accp[8];
  #pragma unroll
  for (int s = 0; s < 8; s++){ acc0[s]=0.f; acc1[s]=0.f; accp[s]=0.f; }
  int cpar = lane & 1;
  for (int jj = wid; jj < jn; jj += 4){
    int j = j0 + jj;
    float av0 = p.A_V[((long)(b*NT+j))*DD + d0];
    float av1 = p.A_V[((long)(b*NT+j))*DD + d1];
    float ag0 = p.ag[(b*NT+j)*2], ag1 = p.ag[(b*NT+j)*2+1];
    float agc = cpar ? ag1 : ag0;
    #pragma unroll
    for (int s = 0; s < 8; s++){
      float rel0 = (ag0 - spss[s][0])*spss[s][2];
      float rel1 = (ag1 - spss[s][1])*spss[s][3];
      float a = atile[s][jj];
      float hv0 = fmaxf(fmaf(rel0,wg00, fmaf(rel1,wg10, av0)), 0.f);
      float hv1 = fmaxf(fmaf(rel0,wg01, fmaf(rel1,wg11, av1)), 0.f);
      acc0[s] = fmaf(a, hv0, acc0[s]);
      acc1[s] = fmaf(a, hv1, acc1[s]);
      if (lane < 2) accp[s] = fmaf(a, agc, accp[s]);
    }
  }
  #pragma unroll
  for (int s = 0; s < 8; s++){ hpart[wid][s][d0] = acc0[s]; hpart[wid][s][d1] = acc1[s]; }
  if (lane < 2)
    for (int s = 0; s < 8; s++) ppart[wid][s][lane] = accp[s];
  __syncthreads();
  for (int f = tid; f < 8*128; f += 256){
    int s = f >> 7, d = f & 127;
    p.hbar_part[((b*8+tile)*NS+s)*DD+d] = hpart[0][s][d]+hpart[1][s][d]+hpart[2][s][d]+hpart[3][s][d];
  }
  if (tid < 16){
    int s = tid >> 1, c = tid & 1;
    p.Sp_part[((b*8+tile)*NS+s)*2+c] = ppart[0][s][c]+ppart[1][s][c]+ppart[2][s][c]+ppart[3][s][c];
  }
}

// ---------- reduce partials -> hbar, Sp_new; then S_s (needs Sp_new, per-bs only) ----------
__global__ __launch_bounds__(128) void k6r(PP p, float* Sp_new, float* Ss_new){
  int bs = blockIdx.x; int b = bs >> 3, s = bs & 7, d = threadIdx.x;
  float v = 0.f;
  for (int t = 0; t < 8; t++) v += p.hbar_part[((b*8+t)*NS+s)*DD+d];
  p.hbar[bs*DD+d] = v;
  __shared__ float spl[2];
  if (d < 2){
    float u = 0.f;
    for (int t = 0; t < 8; t++) u += p.Sp_part[((b*8+t)*NS+s)*2+d];
    Sp_new[bs*2+d] = u; spl[d] = u;
  }
  __syncthreads();
  float sp0 = spl[0], sp1 = spl[1];
  float q0 = 0.f, q1 = 0.f;
  for (int j = d; j < NT; j += 128){
    float at = p.attn[bs*NT+j];
    float e0 = p.ag[(b*NT+j)*2]   - sp0;
    float e1 = p.ag[(b*NT+j)*2+1] - sp1;
    q0 = fmaf(at, e0*e0, q0); q1 = fmaf(at, e1*e1, q1);
  }
  for (int m = 1; m < 64; m <<= 1){ q0 += __shfl_xor(q0, m); q1 += __shfl_xor(q1, m); }
  __shared__ float rr[2][2];
  if ((d & 63) == 0){ rr[d>>6][0] = q0; rr[d>>6][1] = q1; }
  __syncthreads();
  if (d == 0){
    Ss_new[bs*2+0] = sqrtf(rr[0][0]+rr[1][0]);
    Ss_new[bs*2+1] = sqrtf(rr[0][1]+rr[1][1]);
  }
}

// ---------- updates = hbar@Wf2+bf2; GRU; residual pre-LN MLP ----------
__global__ __launch_bounds__(128) void k7_update(PP p){
  int bs = blockIdx.x, d = threadIdx.x;
  __shared__ float hb[128], upd[128], hprev[128], y[128], h1[512];
  __shared__ float rr[2][2];
  hb[d] = p.hbar[bs*DD+d]; hprev[d] = p.slots[bs*DD+d];
  __syncthreads();
  float a = p.bf2[d];
  for (int kk = 0; kk < DD; kk++) a = fmaf(hb[kk], p.Wf2[kk*DD+d], a);
  upd[d] = a;
  __syncthreads();
  float gi[3], gh[3];
  #pragma unroll
  for (int i = 0; i < 3; i++){ gi[i] = p.gru_b_ih[d+128*i]; gh[i] = p.gru_b_hh[d+128*i]; }
  for (int kk = 0; kk < DD; kk++){
    float xv = upd[kk], hv = hprev[kk];
    #pragma unroll
    for (int i = 0; i < 3; i++){
      gi[i] = fmaf(xv, p.gru_w_ih[kk*384 + d+128*i], gi[i]);
      gh[i] = fmaf(hv, p.gru_w_hh[kk*384 + d+128*i], gh[i]);
    }
  }
  float r = 1.f/(1.f+expf(-(gi[0]+gh[0])));
  float z = 1.f/(1.f+expf(-(gi[1]+gh[1])));
  float n = tanhf(gi[2] + r*gh[2]);
  float hnew = (1.f-z)*n + z*hprev[d];
  // LN
  float s = hnew, s2 = hnew*hnew;
  for (int m = 1; m < 64; m <<= 1){ s += __shfl_xor(s, m); s2 += __shfl_xor(s2, m); }
  if ((d & 63) == 0){ rr[d>>6][0] = s; rr[d>>6][1] = s2; }
  __syncthreads();
  s = rr[0][0]+rr[1][0]; s2 = rr[0][1]+rr[1][1];
  float mean = s*(1.f/DD), var = s2*(1.f/DD)-mean*mean, rstd = rsqrtf(var+1e-5f);
  y[d] = (hnew-mean)*rstd*p.mlp_ln_g[d] + p.mlp_ln_b[d];
  __syncthreads();
  #pragma unroll
  for (int i = 0; i < 4; i++){
    int o = d + 128*i;
    float acc = p.mlp_b1[o];
    for (int kk = 0; kk < DD; kk++) acc = fmaf(y[kk], p.mlp_w1[kk*512+o], acc);
    h1[o] = fmaxf(acc, 0.f);
  }
  __syncthreads();
  float acc2 = p.mlp_b2[d];
  for (int o = 0; o < 512; o++) acc2 = fmaf(h1[o], p.mlp_w2[o*DD+d], acc2);
  p.slots[bs*DD+d] = hnew + acc2;
}

// ---------- final projection ----------
__global__ __launch_bounds__(128) void k8_final(PP p){
  int bs = blockIdx.x, d = threadIdx.x;
  __shared__ float sl[128];
  sl[d] = p.slots[bs*DD+d];
  __syncthreads();
  float a = p.fin_b[d];
  for (int kk = 0; kk < DD; kk++) a = fmaf(sl[kk], p.fin_w[kk*DD+d], a);
  p.out[bs*DD+d] = a;
}

// ---------- attn center-frame copy ----------
__global__ void k8_attn(PP p){
  int i = blockIdx.x*256 + threadIdx.x;
  if (i < 8*NS*NT){
    int clip = i / (NS*NT);
    int rem  = i % (NS*NT);
    int b = clip*5 + 2;
    p.out[NB*NS*DD + i] = p.attn[b*NS*NT + rem];
  }
}

extern "C" void kernel_launch(void* const* d_in, const int* in_sizes, int n_in,
                              void* d_out, int out_size, void* d_ws, size_t ws_size,
                              hipStream_t stream){
  PP p;
  p.inputs=(const float*)d_in[0]; p.tok_idx=(const int*)d_in[1]; p.abs_grid=(const float*)d_in[2];
  p.slots_init=(const float*)d_in[3]; p.Sp_init=(const float*)d_in[4]; p.Ss_init=(const float*)d_in[5];
  p.WQ=(const float*)d_in[6]; p.ln_g=(const float*)d_in[7]; p.ln_b=(const float*)d_in[8];
  p.gru_w_ih=(const float*)d_in[9]; p.gru_w_hh=(const float*)d_in[10];
  p.gru_b_ih=(const float*)d_in[11]; p.gru_b_hh=(const float*)d_in[12];
  p.mlp_ln_g=(const float*)d_in[13]; p.mlp_ln_b=(const float*)d_in[14];
  p.mlp_w1=(const float*)d_in[15]; p.mlp_b1=(const float*)d_in[16];
  p.mlp_w2=(const float*)d_in[17]; p.mlp_b2=(const float*)d_in[18];
  p.WK=(const float*)d_in[19]; p.WV=(const float*)d_in[20]; p.Wg=(const float*)d_in[21]; p.bg=(const float*)d_in[22];
  p.Wf1=(const float*)d_in[23]; p.bf1=(const float*)d_in[24]; p.Wf2=(const float*)d_in[25]; p.bf2=(const float*)d_in[26];
  p.im_ln1_g=(const float*)d_in[27]; p.im_ln1_b=(const float*)d_in[28];
  p.im_w1=(const float*)d_in[29]; p.im_b1=(const float*)d_in[30];
  p.im_w2=(const float*)d_in[31]; p.im_b2=(const float*)d_in[32];
  p.im_ln2_g=(const float*)d_in[33]; p.im_ln2_b=(const float*)d_in[34];
  p.fin_w=(const float*)d_in[35]; p.fin_b=(const float*)d_in[36];

  float* w = (float*)d_ws;
  size_t need = 0;
  auto alloc = [&](size_t nfl){ float* r = w + need; need += nfl; return r; };
  p.x    = alloc((size_t)NTOT*DD);
  p.A_K  = alloc((size_t)NTOT*DD);
  p.A_V  = alloc((size_t)NTOT*DD);
  p.ag   = alloc((size_t)NTOT*2);
  p.WKf  = alloc(DD*DD);
  p.WVf  = alloc(DD*DD);
  p.Wg1  = alloc(2*DD);
  p.c1   = alloc(DD);
  p.Wf2T = alloc(DD*DD);
  p.slots= alloc(NB*NS*DD);
  p.Sp0  = alloc(NB*NS*2);
  p.Sp1  = alloc(NB*NS*2);
  p.Ss0  = alloc(NB*NS*2);
  p.Ss1  = alloc(NB*NS*2);
  p.qW   = alloc(NB*NS*DD);
  p.qb   = alloc(NB*NS);
  p.dots = alloc((size_t)NB*NS*NT);
  p.attn = alloc((size_t)NB*NS*NT);
  p.hbar_part = alloc((size_t)NB*8*NS*DD);
  p.Sp_part   = alloc((size_t)NB*8*NS*2);
  p.hbar = alloc(NB*NS*DD);
  p.out = (float*)d_out;
  if (ws_size < need*sizeof(float)){
    fprintf(stderr, "kernel_launch: ws too small (%zu < %zu)\n", ws_size, need*sizeof(float));
    return;
  }

  prep_weights<<<dim3(DD), dim3(DD), 0, stream>>>(p);
  init_state<<<dim3((NB*NS*DD+255)/256), dim3(256), 0, stream>>>(p);
  gather_ag<<<dim3((NTOT+255)/256), dim3(256), 0, stream>>>(p);
  k1_initial_mlp<<<dim3((NTOT+15)/16), dim3(256), 0, stream>>>(p);
  k2_proj<<<dim3((NTOT+31)/32), dim3(256), 0, stream>>>(p);

  float* Sp[2] = {p.Sp0, p.Sp1};
  float* Ss[2] = {p.Ss0, p.Ss1};
  int cur = 0;
  for (int t = 0; t < 4; t++){
    k3_slots<<<dim3(NB*NS), dim3(128), 0, stream>>>(p);
    k4_dots<<<dim3(NB*7), dim3(256), 0, stream>>>(p, Sp[cur], Ss[cur]);
    k5_softmax<<<dim3(NB), dim3(256), 0, stream>>>(p);
    if (t < 3){
      k6a<<<dim3(NB*8), dim3(256), 0, stream>>>(p, Sp[cur], Ss[cur]);
      k6r<<<dim3(NB*NS), dim3(128), 0, stream>>>(p, Sp[cur^1], Ss[cur^1]);
      k7_update<<<dim3(NB*NS), dim3(128), 0, stream>>>(p);
      cur ^= 1;
    }
  }
  k8_final<<<dim3(NB*NS), dim3(128), 0, stream>>>(p);
  k8_attn<<<dim3((8*NS*NT+255)/256), dim3(256), 0, stream>>>(p);
}

// Round 2
// 477.321 us; speedup vs baseline: 2.2777x; 2.2777x over previous
//
#include <hip/hip_runtime.h>
#include <cstdio>

#define NB 40
#define NS 8
#define NT 441
#define DIN 768
#define DD 128
#define NTOT (NB*NT)
#define FSCALE 0.08838834764831843f

typedef short s8v __attribute__((ext_vector_type(8)));
typedef float f4v __attribute__((ext_vector_type(4)));

__device__ inline ushort f2bf(float f){
  unsigned u = __float_as_uint(f);
  unsigned r = (u + 0x7fffu + ((u >> 16) & 1u)) >> 16;
  return (ushort)r;
}
__device__ inline float bf2f(ushort h){ return __uint_as_float(((unsigned)h) << 16); }

struct PP {
  const float *inputs; const int *tok_idx; const float *abs_grid;
  const float *slots_init, *Sp_init, *Ss_init;
  const float *WQ, *ln_g, *ln_b;
  const float *gru_w_ih, *gru_w_hh, *gru_b_ih, *gru_b_hh;
  const float *mlp_ln_g, *mlp_ln_b, *mlp_w1, *mlp_b1, *mlp_w2, *mlp_b2;
  const float *WK, *WV, *Wg, *bg, *Wf1, *bf1, *Wf2, *bf2;
  const float *im_ln1_g, *im_ln1_b, *im_w1, *im_b1, *im_w2, *im_b2, *im_ln2_g, *im_ln2_b;
  const float *fin_w, *fin_b;
  float *x, *A_K, *A_V, *ag, *WKf, *WVf, *Wg1, *c1, *Wf2T;
  float *slots, *Sp0, *Sp1, *Ss0, *Ss1, *qW, *qb, *dots, *attn;
  float *hbar_part, *Sp_part, *hbar;
  ushort *xnh, *xnl, *hh, *hl, *W1Th, *W1Tl, *W2Th, *W2Tl;
  float *out;
};

// ---------- weight prep: WKf=WK@Wf1, WVf=WV@Wf1, Wg1=Wg@Wf1, c1=bg@Wf1+bf1, Wf2T ----------
__global__ __launch_bounds__(128) void prep_weights(PP p){
  int r = blockIdx.x, d = threadIdx.x;
  float accK = 0.f, accV = 0.f;
  for (int kk = 0; kk < DD; kk++){
    float w = p.Wf1[kk*DD + d];
    accK = fmaf(p.WK[r*DD+kk], w, accK);
    accV = fmaf(p.WV[r*DD+kk], w, accV);
  }
  p.WKf[r*DD+d] = accK; p.WVf[r*DD+d] = accV;
  if (r < 2){
    float a = 0.f;
    for (int kk = 0; kk < DD; kk++) a = fmaf(p.Wg[r*DD+kk], p.Wf1[kk*DD+d], a);
    p.Wg1[r*DD+d] = a;
  }
  if (r == 2){
    float a = 0.f;
    for (int kk = 0; kk < DD; kk++) a = fmaf(p.bg[kk], p.Wf1[kk*DD+d], a);
    p.c1[d] = a + p.bf1[d];
  }
  p.Wf2T[d*DD + r] = p.Wf2[r*DD + d];
}

// ---------- transpose + bf16 split: WT[n][k] = W[k][n] ----------
__global__ __launch_bounds__(256) void transpose_split(const float* __restrict__ W,
                                                       ushort* __restrict__ WTh,
                                                       ushort* __restrict__ WTl,
                                                       int K, int N){
  __shared__ float tile[64][65];
  int tid = threadIdx.x;
  int k0 = blockIdx.x * 64, n0 = blockIdx.y * 64;
  #pragma unroll
  for (int i = 0; i < 4; i++){
    int k = i*16 + (tid >> 4);
    int n4 = (tid & 15) * 4;
    float4 v = *(const float4*)(W + (long)(k0+k)*N + n0 + n4);
    tile[k][n4+0] = v.x; tile[k][n4+1] = v.y; tile[k][n4+2] = v.z; tile[k][n4+3] = v.w;
  }
  __syncthreads();
  #pragma unroll
  for (int i = 0; i < 4; i++){
    int n = i*16 + (tid >> 4);
    int k4 = (tid & 15) * 4;
    ushort4 h4, l4;
    float v0 = tile[k4+0][n], v1 = tile[k4+1][n], v2 = tile[k4+2][n], v3 = tile[k4+3][n];
    h4.x = f2bf(v0); l4.x = f2bf(v0 - bf2f(h4.x));
    h4.y = f2bf(v1); l4.y = f2bf(v1 - bf2f(h4.y));
    h4.z = f2bf(v2); l4.z = f2bf(v2 - bf2f(h4.z));
    h4.w = f2bf(v3); l4.w = f2bf(v3 - bf2f(h4.w));
    *(ushort4*)(WTh + (long)(n0+n)*K + k0 + k4) = h4;
    *(ushort4*)(WTl + (long)(n0+n)*K + k0 + k4) = l4;
  }
}

// ---------- LN1 + bf16 hi/lo split of normalized inputs ----------
__global__ __launch_bounds__(256) void ln1_split(PP p){
  int tok = blockIdx.x*4 + (threadIdx.x >> 6);
  int l = threadIdx.x & 63;
  const float* src = p.inputs + (long)tok*DIN;
  float4 v[3];
  float s = 0.f, s2 = 0.f;
  #pragma unroll
  for (int pp = 0; pp < 3; pp++){
    v[pp] = *(const float4*)(src + pp*256 + l*4);
    s  += v[pp].x + v[pp].y + v[pp].z + v[pp].w;
    s2 += v[pp].x*v[pp].x + v[pp].y*v[pp].y + v[pp].z*v[pp].z + v[pp].w*v[pp].w;
  }
  #pragma unroll
  for (int m = 1; m < 64; m <<= 1){ s += __shfl_xor(s, m); s2 += __shfl_xor(s2, m); }
  float mean = s*(1.f/DIN), var = s2*(1.f/DIN) - mean*mean;
  float rstd = rsqrtf(var + 1e-5f);
  #pragma unroll
  for (int pp = 0; pp < 3; pp++){
    int idx = pp*256 + l*4;
    float4 g = *(const float4*)(p.im_ln1_g + idx);
    float4 b = *(const float4*)(p.im_ln1_b + idx);
    float y0 = (v[pp].x-mean)*rstd*g.x + b.x;
    float y1 = (v[pp].y-mean)*rstd*g.y + b.y;
    float y2 = (v[pp].z-mean)*rstd*g.z + b.z;
    float y3 = (v[pp].w-mean)*rstd*g.w + b.w;
    ushort4 h4, l4;
    h4.x = f2bf(y0); l4.x = f2bf(y0 - bf2f(h4.x));
    h4.y = f2bf(y1); l4.y = f2bf(y1 - bf2f(h4.y));
    h4.z = f2bf(y2); l4.z = f2bf(y2 - bf2f(h4.z));
    h4.w = f2bf(y3); l4.w = f2bf(y3 - bf2f(h4.w));
    *(ushort4*)(p.xnh + (long)tok*DIN + idx) = h4;
    *(ushort4*)(p.xnl + (long)tok*DIN + idx) = l4;
  }
}

// ---------- split-bf16 MFMA GEMM: C[M x N] = A[M x 768] * B^T-rows, 3-pass hi/lo ----------
// EPI=1: bias+relu, re-split to Ch/Cl (for GEMM2 input).  EPI=2: bias + LN(128) -> Xout f32.
template<int EPI>
__global__ __launch_bounds__(256) void gemm_split(
    const ushort* __restrict__ Ah, const ushort* __restrict__ Al,
    const ushort* __restrict__ Bh, const ushort* __restrict__ Bl,
    const float* __restrict__ bias,
    ushort* __restrict__ Ch, ushort* __restrict__ Cl,
    float* __restrict__ Xout, const float* __restrict__ g2, const float* __restrict__ b2,
    int M)
{
  __shared__ __align__(16) char smem[64*132*4];
  ushort* As = (ushort*)smem;               // [2][64][40]
  ushort* Bs = (ushort*)(smem + 10240);     // [2][128][40]
  int tid = threadIdx.x;
  int n0 = blockIdx.x * 128, m0 = blockIdx.y * 64;
  int w = tid >> 6, lane = tid & 63;
  f4v acc[4][2];
  #pragma unroll
  for (int mf = 0; mf < 4; mf++)
    #pragma unroll
    for (int nf = 0; nf < 2; nf++) acc[mf][nf] = (f4v)(0.f);

  for (int kb = 0; kb < DIN; kb += 32){
    __syncthreads();
    #pragma unroll
    for (int i = 0; i < 2; i++){
      int c = tid + i*256;
      int s = c >> 8, r = (c >> 2) & 63, kg = c & 3;
      int gr = min(m0 + r, M-1);
      const float4 va = *(const float4*)((s ? Al : Ah) + (long)gr*DIN + kb + kg*8);
      *(float4*)(As + s*2560 + r*40 + kg*8) = va;
    }
    #pragma unroll
    for (int i = 0; i < 4; i++){
      int c = tid + i*256;
      int s = c >> 9, r = (c >> 2) & 127, kg = c & 3;
      const float4 vb = *(const float4*)((s ? Bl : Bh) + (long)(n0 + r)*DIN + kb + kg*8);
      *(float4*)(Bs + s*5120 + r*40 + kg*8) = vb;
    }
    __syncthreads();
    int kg = lane >> 4, rA = lane & 15;
    s8v a0[4], a1[4], b0[2], b1[2];
    #pragma unroll
    for (int mf = 0; mf < 4; mf++){
      a0[mf] = *(const s8v*)(As +        (mf*16 + rA)*40 + kg*8);
      a1[mf] = *(const s8v*)(As + 2560 + (mf*16 + rA)*40 + kg*8);
    }
    #pragma unroll
    for (int nf = 0; nf < 2; nf++){
      int rb = w*32 + nf*16 + rA;
      b0[nf] = *(const s8v*)(Bs +        rb*40 + kg*8);
      b1[nf] = *(const s8v*)(Bs + 5120 + rb*40 + kg*8);
    }
    #pragma unroll
    for (int mf = 0; mf < 4; mf++)
      #pragma unroll
      for (int nf = 0; nf < 2; nf++){
        acc[mf][nf] = __builtin_amdgcn_mfma_f32_16x16x32_bf16(a0[mf], b0[nf], acc[mf][nf], 0, 0, 0);
        acc[mf][nf] = __builtin_amdgcn_mfma_f32_16x16x32_bf16(a0[mf], b1[nf], acc[mf][nf], 0, 0, 0);
        acc[mf][nf] = __builtin_amdgcn_mfma_f32_16x16x32_bf16(a1[mf], b0[nf], acc[mf][nf], 0, 0, 0);
      }
  }

  int rbase = (lane >> 4) * 4, cn = lane & 15;
  if (EPI == 1){
    #pragma unroll
    for (int mf = 0; mf < 4; mf++)
      #pragma unroll
      for (int nf = 0; nf < 2; nf++){
        int n = n0 + w*32 + nf*16 + cn;
        float bs = bias[n];
        #pragma unroll
        for (int r = 0; r < 4; r++){
          int m = m0 + mf*16 + rbase + r;
          if (m < M){
            float v = fmaxf(acc[mf][nf][r] + bs, 0.f);
            ushort h = f2bf(v);
            Ch[(long)m*DIN + n] = h;
            Cl[(long)m*DIN + n] = f2bf(v - bf2f(h));
          }
        }
      }
  } else {
    __syncthreads();
    float* Dl = (float*)smem;   // [64][132]
    #pragma unroll
    for (int mf = 0; mf < 4; mf++)
      #pragma unroll
      for (int nf = 0; nf < 2; nf++){
        int n = w*32 + nf*16 + cn;
        float bs = bias[n];
        #pragma unroll
        for (int r = 0; r < 4; r++)
          Dl[(mf*16 + rbase + r)*132 + n] = acc[mf][nf][r] + bs;
      }
    __syncthreads();
    for (int rr = 0; rr < 16; rr++){
      int row = w*16 + rr;
      float e0 = Dl[row*132 + lane], e1 = Dl[row*132 + 64 + lane];
      float s = e0 + e1, s2 = e0*e0 + e1*e1;
      #pragma unroll
      for (int m2 = 1; m2 < 64; m2 <<= 1){ s += __shfl_xor(s, m2); s2 += __shfl_xor(s2, m2); }
      float mean = s*(1.f/DD), var = s2*(1.f/DD) - mean*mean;
      float rstd = rsqrtf(var + 1e-5f);
      int m = m0 + row;
      if (m < M){
        Xout[(long)m*DD + lane]      = (e0-mean)*rstd*g2[lane]      + b2[lane];
        Xout[(long)m*DD + 64 + lane] = (e1-mean)*rstd*g2[64 + lane] + b2[64 + lane];
      }
    }
  }
}

// ---------- state init ----------
__global__ void init_state(PP p){
  int i = blockIdx.x*256 + threadIdx.x;
  if (i < NB*NS*DD) p.slots[i] = p.slots_init[i & (NS*DD-1)];
  if (i < NB*NS*2){
    p.Sp0[i] = p.Sp_init[i & (NS*2-1)];
    p.Ss0[i] = p.Ss_init[i & (NS*2-1)];
  }
}

// ---------- gather abs_grid per token ----------
__global__ void gather_ag(PP p){
  int i = blockIdx.x*256 + threadIdx.x;
  if (i < NTOT){
    int idx = p.tok_idx[i];
    p.ag[i*2+0] = p.abs_grid[idx*2+0];
    p.ag[i*2+1] = p.abs_grid[idx*2+1];
  }
}

// ---------- A_K = x@WKf + c1 ; A_V = x@WVf + c1 ----------
__global__ __launch_bounds__(256) void k2_proj(PP p){
  __shared__ float xt[32][132];
  int tid = threadIdx.x; int g0 = blockIdx.x * 32;
  for (int f = tid; f < 32*32; f += 256){
    int tok = f >> 5, pos = (f & 31) * 4;
    int gt = g0 + tok;
    float4 v = (gt < NTOT) ? *(const float4*)(p.x + (long)gt*DD + pos)
                           : make_float4(0.f,0.f,0.f,0.f);
    *(float4*)&xt[tok][pos] = v;
  }
  __syncthreads();
  int d = tid & 127, grp = tid >> 7;
  float aK[16], aV[16];
  float c1v = p.c1[d];
  #pragma unroll
  for (int t = 0; t < 16; t++){ aK[t] = c1v; aV[t] = c1v; }
  for (int kk = 0; kk < DD; kk += 4){
    float k0 = p.WKf[(kk+0)*DD+d], k1 = p.WKf[(kk+1)*DD+d], k2 = p.WKf[(kk+2)*DD+d], k3 = p.WKf[(kk+3)*DD+d];
    float v0 = p.WVf[(kk+0)*DD+d], v1 = p.WVf[(kk+1)*DD+d], v2 = p.WVf[(kk+2)*DD+d], v3 = p.WVf[(kk+3)*DD+d];
    #pragma unroll
    for (int t = 0; t < 16; t++){
      float4 xv = *(const float4*)&xt[grp*16+t][kk];
      aK[t] = fmaf(xv.x,k0, fmaf(xv.y,k1, fmaf(xv.z,k2, fmaf(xv.w,k3, aK[t]))));
      aV[t] = fmaf(xv.x,v0, fmaf(xv.y,v1, fmaf(xv.z,v2, fmaf(xv.w,v3, aV[t]))));
    }
  }
  #pragma unroll
  for (int t = 0; t < 16; t++){
    int gt = g0 + grp*16 + t;
    if (gt < NTOT){ p.A_K[(long)gt*DD+d] = aK[t]; p.A_V[(long)gt*DD+d] = aV[t]; }
  }
}

// ---------- per-(b,s): sn=LN(slots), q=sn@WQ, qW=Wf2@q, qb=SCALE*(bf2.q) ----------
__global__ __launch_bounds__(128) void k3_slots(PP p){
  int bs = blockIdx.x, d = threadIdx.x;
  __shared__ float sn[128], q[128];
  __shared__ float rs[2][2];
  float v = p.slots[bs*DD+d];
  float s = v, s2 = v*v;
  for (int m = 1; m < 64; m <<= 1){ s += __shfl_xor(s, m); s2 += __shfl_xor(s2, m); }
  if ((d & 63) == 0){ rs[d>>6][0] = s; rs[d>>6][1] = s2; }
  __syncthreads();
  s = rs[0][0] + rs[1][0]; s2 = rs[0][1] + rs[1][1];
  float mean = s*(1.f/DD), var = s2*(1.f/DD) - mean*mean, rstd = rsqrtf(var + 1e-5f);
  sn[d] = (v-mean)*rstd*p.ln_g[d] + p.ln_b[d];
  __syncthreads();
  float acc = 0.f;
  for (int kk = 0; kk < DD; kk++) acc = fmaf(sn[kk], p.WQ[kk*DD+d], acc);
  q[d] = acc;
  __syncthreads();
  float a2 = 0.f;
  for (int dd = 0; dd < DD; dd++) a2 = fmaf(q[dd], p.Wf2T[dd*DD+d], a2);
  p.qW[bs*DD+d] = a2;
  float pb = p.bf2[d]*q[d];
  for (int m = 1; m < 64; m <<= 1) pb += __shfl_xor(pb, m);
  if ((d & 63) == 0) rs[d>>6][0] = pb;
  __syncthreads();
  if (d == 0) p.qb[bs] = (rs[0][0] + rs[1][0]) * FSCALE;
}

// ---------- dots ----------
__global__ __launch_bounds__(256) void k4_dots(PP p, const float* Sp, const float* Ss){
  int b = blockIdx.x / 7, tile = blockIdx.x % 7;
  int tid = threadIdx.x, wid = tid >> 6, lane = tid & 63;
  int tl = lane >> 2, dg = lane & 3;
  __shared__ float qws[8][132];
  __shared__ float spss[8][4];
  __shared__ float qbs[8];
  for (int f = tid; f < 8*128; f += 256){
    int s = f >> 7, d = f & 127;
    qws[s][(d&31)*4 + (d>>5)] = p.qW[(b*NS+s)*DD+d];
  }
  if (tid < 8) qbs[tid] = p.qb[b*NS+tid];
  if (tid < 32){
    int s = tid >> 2, c = tid & 3;
    spss[s][c] = (c < 2) ? Sp[(b*NS+s)*2+c] : 1.f/(Ss[(b*NS+s)*2+(c-2)]*5.0f);
  }
  __syncthreads();
  int j = tile*64 + wid*16 + tl;
  bool valid = j < NT;
  int jj = valid ? j : 0;
  float aa[32], w0[32], w1[32];
  {
    const float* src = p.A_K + ((long)(b*NT+jj))*DD + dg*32;
    #pragma unroll
    for (int i4 = 0; i4 < 8; i4++){
      float4 t = *(const float4*)(src + i4*4);
      aa[i4*4+0]=t.x; aa[i4*4+1]=t.y; aa[i4*4+2]=t.z; aa[i4*4+3]=t.w;
    }
    #pragma unroll
    for (int i4 = 0; i4 < 8; i4++){
      float4 t0 = *(const float4*)(p.Wg1 + dg*32 + i4*4);
      float4 t1 = *(const float4*)(p.Wg1 + DD + dg*32 + i4*4);
      w0[i4*4+0]=t0.x; w0[i4*4+1]=t0.y; w0[i4*4+2]=t0.z; w0[i4*4+3]=t0.w;
      w1[i4*4+0]=t1.x; w1[i4*4+1]=t1.y; w1[i4*4+2]=t1.z; w1[i4*4+3]=t1.w;
    }
  }
  float ag0 = p.ag[(b*NT+jj)*2], ag1 = p.ag[(b*NT+jj)*2+1];
  #pragma unroll
  for (int s = 0; s < 8; s++){
    float rel0 = (ag0 - spss[s][0])*spss[s][2];
    float rel1 = (ag1 - spss[s][1])*spss[s][3];
    float acc = 0.f;
    #pragma unroll
    for (int i = 0; i < 32; i++){
      float hk = fmaxf(fmaf(rel0, w0[i], fmaf(rel1, w1[i], aa[i])), 0.f);
      acc = fmaf(hk, qws[s][i*4+dg], acc);
    }
    acc += __shfl_xor(acc, 1); acc += __shfl_xor(acc, 2);
    if (dg == 0 && valid) p.dots[(b*NS+s)*NT + j] = acc*FSCALE + qbs[s];
  }
}

// ---------- softmax over s, +eps, renormalize over j ----------
__global__ __launch_bounds__(256) void k5_softmax(PP p){
  int b = blockIdx.x, tid = threadIdx.x;
  float a0[8], a1[8];
  float psum[8];
  #pragma unroll
  for (int s = 0; s < 8; s++) psum[s] = 0.f;
  bool has1 = (tid + 256) < NT;
  {
    int j = tid;
    float dv[8]; float m = -1e30f;
    #pragma unroll
    for (int s = 0; s < 8; s++){ dv[s] = p.dots[(b*NS+s)*NT+j]; m = fmaxf(m, dv[s]); }
    float tot = 0.f;
    #pragma unroll
    for (int s = 0; s < 8; s++){ dv[s] = expf(dv[s]-m); tot += dv[s]; }
    float inv = 1.f/tot;
    #pragma unroll
    for (int s = 0; s < 8; s++){ a0[s] = dv[s]*inv + 1e-8f; psum[s] += a0[s]; }
  }
  if (has1){
    int j = tid + 256;
    float dv[8]; float m = -1e30f;
    #pragma unroll
    for (int s = 0; s < 8; s++){ dv[s] = p.dots[(b*NS+s)*NT+j]; m = fmaxf(m, dv[s]); }
    float tot = 0.f;
    #pragma unroll
    for (int s = 0; s < 8; s++){ dv[s] = expf(dv[s]-m); tot += dv[s]; }
    float inv = 1.f/tot;
    #pragma unroll
    for (int s = 0; s < 8; s++){ a1[s] = dv[s]*inv + 1e-8f; psum[s] += a1[s]; }
  }
  #pragma unroll
  for (int s = 0; s < 8; s++)
    for (int m2 = 1; m2 < 64; m2 <<= 1) psum[s] += __shfl_xor(psum[s], m2);
  __shared__ float wsum[4][8];
  __shared__ float sums[8];
  if ((tid & 63) == 0)
    for (int s = 0; s < 8; s++) wsum[tid>>6][s] = psum[s];
  __syncthreads();
  if (tid < 8) sums[tid] = wsum[0][tid]+wsum[1][tid]+wsum[2][tid]+wsum[3][tid];
  __syncthreads();
  {
    int j = tid;
    #pragma unroll
    for (int s = 0; s < 8; s++) p.attn[(b*NS+s)*NT+j] = a0[s]/sums[s];
  }
  if (has1){
    int j = tid + 256;
    #pragma unroll
    for (int s = 0; s < 8; s++) p.attn[(b*NS+s)*NT+j] = a1[s]/sums[s];
  }
}

// ---------- hbar partials and S_p partials ----------
__global__ __launch_bounds__(256) void k6a(PP p, const float* Sp, const float* Ss){
  int b = blockIdx.x >> 3, tile = blockIdx.x & 7;
  int tid = threadIdx.x, wid = tid >> 6, lane = tid & 63;
  int j0 = tile*56; int jn = min(NT, j0+56) - j0;
  __shared__ float atile[8][56];
  __shared__ float spss[8][4];
  __shared__ float hpart[4][8][128];
  __shared__ float ppart[4][8][2];
  for (int f = tid; f < 8*56; f += 256){
    int s = f/56, jj = f%56;
    atile[s][jj] = (j0+jj < NT) ? p.attn[(b*NS+s)*NT + j0+jj] : 0.f;
  }
  if (tid < 32){
    int s = tid >> 2, c = tid & 3;
    spss[s][c] = (c < 2) ? Sp[(b*NS+s)*2+c] : 1.f/(Ss[(b*NS+s)*2+(c-2)]*5.0f);
  }
  __syncthreads();
  int d0 = lane, d1 = lane + 64;
  float wg00 = p.Wg1[d0], wg10 = p.Wg1[DD+d0], wg01 = p.Wg1[d1], wg11 = p.Wg1[DD+d1];
  float acc0[8], acc1[8], accp[8];
  #pragma unroll
  for (int s = 0; s < 8; s++){ acc0[s]=0.f; acc1[s]=0.f; accp[s]=0.f; }
  int cpar = lane & 1;
  for (int jj = wid; jj < jn; jj += 4){
    int j = j0 + jj;
    float av0 = p.A_V[((long)(b*NT+j))*DD + d0];
    float av1 = p.A_V[((long)(b*NT+j))*DD + d1];
    float ag0 = p.ag[(b*NT+j)*2], ag1 = p.ag[(b*NT+j)*2+1];
    float agc = cpar ? ag1 : ag0;
    #pragma unroll
    for (int s = 0; s < 8; s++){
      float rel0 = (ag0 - spss[s][0])*spss[s][2];
      float rel1 = (ag1 - spss[s][1])*spss[s][3];
      float a = atile[s][jj];
      float hv0 = fmaxf(fmaf(rel0,wg00, fmaf(rel1,wg10, av0)), 0.f);
      float hv1 = fmaxf(fmaf(rel0,wg01, fmaf(rel1,wg11, av1)), 0.f);
      acc0[s] = fmaf(a, hv0, acc0[s]);
      acc1[s] = fmaf(a, hv1, acc1[s]);
      if (lane < 2) accp[s] = fmaf(a, agc, accp[s]);
    }
  }
  #pragma unroll
  for (int s = 0; s < 8; s++){ hpart[wid][s][d0] = acc0[s]; hpart[wid][s][d1] = acc1[s]; }
  if (lane < 2)
    for (int s = 0; s < 8; s++) ppart[wid][s][lane] = accp[s];
  __syncthreads();
  for (int f = tid; f < 8*128; f += 256){
    int s = f >> 7, d = f & 127;
    p.hbar_part[((b*8+tile)*NS+s)*DD+d] = hpart[0][s][d]+hpart[1][s][d]+hpart[2][s][d]+hpart[3][s][d];
  }
  if (tid < 16){
    int s = tid >> 1, c = tid & 1;
    p.Sp_part[((b*8+tile)*NS+s)*2+c] = ppart[0][s][c]+ppart[1][s][c]+ppart[2][s][c]+ppart[3][s][c];
  }
}

// ---------- reduce partials -> hbar, Sp_new, Ss_new ----------
__global__ __launch_bounds__(128) void k6r(PP p, float* Sp_new, float* Ss_new){
  int bs = blockIdx.x; int b = bs >> 3, s = bs & 7, d = threadIdx.x;
  float v = 0.f;
  for (int t = 0; t < 8; t++) v += p.hbar_part[((b*8+t)*NS+s)*DD+d];
  p.hbar[bs*DD+d] = v;
  __shared__ float spl[2];
  if (d < 2){
    float u = 0.f;
    for (int t = 0; t < 8; t++) u += p.Sp_part[((b*8+t)*NS+s)*2+d];
    Sp_new[bs*2+d] = u; spl[d] = u;
  }
  __syncthreads();
  float sp0 = spl[0], sp1 = spl[1];
  float q0 = 0.f, q1 = 0.f;
  for (int j = d; j < NT; j += 128){
    float at = p.attn[bs*NT+j];
    float e0 = p.ag[(b*NT+j)*2]   - sp0;
    float e1 = p.ag[(b*NT+j)*2+1] - sp1;
    q0 = fmaf(at, e0*e0, q0); q1 = fmaf(at, e1*e1, q1);
  }
  for (int m = 1; m < 64; m <<= 1){ q0 += __shfl_xor(q0, m); q1 += __shfl_xor(q1, m); }
  __shared__ float rr[2][2];
  if ((d & 63) == 0){ rr[d>>6][0] = q0; rr[d>>6][1] = q1; }
  __syncthreads();
  if (d == 0){
    Ss_new[bs*2+0] = sqrtf(rr[0][0]+rr[1][0]);
    Ss_new[bs*2+1] = sqrtf(rr[0][1]+rr[1][1]);
  }
}

// ---------- updates = hbar@Wf2+bf2; GRU; residual pre-LN MLP ----------
__global__ __launch_bounds__(128) void k7_update(PP p){
  int bs = blockIdx.x, d = threadIdx.x;
  __shared__ float hb[128], upd[128], hprev[128], y[128], h1[512];
  __shared__ float rr[2][2];
  hb[d] = p.hbar[bs*DD+d]; hprev[d] = p.slots[bs*DD+d];
  __syncthreads();
  float a = p.bf2[d];
  for (int kk = 0; kk < DD; kk++) a = fmaf(hb[kk], p.Wf2[kk*DD+d], a);
  upd[d] = a;
  __syncthreads();
  float gi[3], gh[3];
  #pragma unroll
  for (int i = 0; i < 3; i++){ gi[i] = p.gru_b_ih[d+128*i]; gh[i] = p.gru_b_hh[d+128*i]; }
  for (int kk = 0; kk < DD; kk++){
    float xv = upd[kk], hv = hprev[kk];
    #pragma unroll
    for (int i = 0; i < 3; i++){
      gi[i] = fmaf(xv, p.gru_w_ih[kk*384 + d+128*i], gi[i]);
      gh[i] = fmaf(hv, p.gru_w_hh[kk*384 + d+128*i], gh[i]);
    }
  }
  float r = 1.f/(1.f+expf(-(gi[0]+gh[0])));
  float z = 1.f/(1.f+expf(-(gi[1]+gh[1])));
  float n = tanhf(gi[2] + r*gh[2]);
  float hnew = (1.f-z)*n + z*hprev[d];
  float s = hnew, s2 = hnew*hnew;
  for (int m = 1; m < 64; m <<= 1){ s += __shfl_xor(s, m); s2 += __shfl_xor(s2, m); }
  if ((d & 63) == 0){ rr[d>>6][0] = s; rr[d>>6][1] = s2; }
  __syncthreads();
  s = rr[0][0]+rr[1][0]; s2 = rr[0][1]+rr[1][1];
  float mean = s*(1.f/DD), var = s2*(1.f/DD)-mean*mean, rstd = rsqrtf(var+1e-5f);
  y[d] = (hnew-mean)*rstd*p.mlp_ln_g[d] + p.mlp_ln_b[d];
  __syncthreads();
  #pragma unroll
  for (int i = 0; i < 4; i++){
    int o = d + 128*i;
    float acc = p.mlp_b1[o];
    for (int kk = 0; kk < DD; kk++) acc = fmaf(y[kk], p.mlp_w1[kk*512+o], acc);
    h1[o] = fmaxf(acc, 0.f);
  }
  __syncthreads();
  float acc2 = p.mlp_b2[d];
  for (int o = 0; o < 512; o++) acc2 = fmaf(h1[o], p.mlp_w2[o*DD+d], acc2);
  p.slots[bs*DD+d] = hnew + acc2;
}

// ---------- final projection ----------
__global__ __launch_bounds__(128) void k8_final(PP p){
  int bs = blockIdx.x, d = threadIdx.x;
  __shared__ float sl[128];
  sl[d] = p.slots[bs*DD+d];
  __syncthreads();
  float a = p.fin_b[d];
  for (int kk = 0; kk < DD; kk++) a = fmaf(sl[kk], p.fin_w[kk*DD+d], a);
  p.out[bs*DD+d] = a;
}

// ---------- attn center-frame copy ----------
__global__ void k8_attn(PP p){
  int i = blockIdx.x*256 + threadIdx.x;
  if (i < 8*NS*NT){
    int clip = i / (NS*NT);
    int rem  = i % (NS*NT);
    int b = clip*5 + 2;
    p.out[NB*NS*DD + i] = p.attn[b*NS*NT + rem];
  }
}

extern "C" void kernel_launch(void* const* d_in, const int* in_sizes, int n_in,
                              void* d_out, int out_size, void* d_ws, size_t ws_size,
                              hipStream_t stream){
  PP p;
  p.inputs=(const float*)d_in[0]; p.tok_idx=(const int*)d_in[1]; p.abs_grid=(const float*)d_in[2];
  p.slots_init=(const float*)d_in[3]; p.Sp_init=(const float*)d_in[4]; p.Ss_init=(const float*)d_in[5];
  p.WQ=(const float*)d_in[6]; p.ln_g=(const float*)d_in[7]; p.ln_b=(const float*)d_in[8];
  p.gru_w_ih=(const float*)d_in[9]; p.gru_w_hh=(const float*)d_in[10];
  p.gru_b_ih=(const float*)d_in[11]; p.gru_b_hh=(const float*)d_in[12];
  p.mlp_ln_g=(const float*)d_in[13]; p.mlp_ln_b=(const float*)d_in[14];
  p.mlp_w1=(const float*)d_in[15]; p.mlp_b1=(const float*)d_in[16];
  p.mlp_w2=(const float*)d_in[17]; p.mlp_b2=(const float*)d_in[18];
  p.WK=(const float*)d_in[19]; p.WV=(const float*)d_in[20]; p.Wg=(const float*)d_in[21]; p.bg=(const float*)d_in[22];
  p.Wf1=(const float*)d_in[23]; p.bf1=(const float*)d_in[24]; p.Wf2=(const float*)d_in[25]; p.bf2=(const float*)d_in[26];
  p.im_ln1_g=(const float*)d_in[27]; p.im_ln1_b=(const float*)d_in[28];
  p.im_w1=(const float*)d_in[29]; p.im_b1=(const float*)d_in[30];
  p.im_w2=(const float*)d_in[31]; p.im_b2=(const float*)d_in[32];
  p.im_ln2_g=(const float*)d_in[33]; p.im_ln2_b=(const float*)d_in[34];
  p.fin_w=(const float*)d_in[35]; p.fin_b=(const float*)d_in[36];

  float* w = (float*)d_ws;
  size_t need = 0;
  auto alloc = [&](size_t nfl){ nfl = (nfl + 3) & ~(size_t)3; float* r = w + need; need += nfl; return r; };
  p.x    = alloc((size_t)NTOT*DD);
  p.A_K  = alloc((size_t)NTOT*DD);
  p.A_V  = alloc((size_t)NTOT*DD);
  p.ag   = alloc((size_t)NTOT*2);
  p.WKf  = alloc(DD*DD);
  p.WVf  = alloc(DD*DD);
  p.Wg1  = alloc(2*DD);
  p.c1   = alloc(DD);
  p.Wf2T = alloc(DD*DD);
  p.slots= alloc(NB*NS*DD);
  p.Sp0  = alloc(NB*NS*2);
  p.Sp1  = alloc(NB*NS*2);
  p.Ss0  = alloc(NB*NS*2);
  p.Ss1  = alloc(NB*NS*2);
  p.qW   = alloc(NB*NS*DD);
  p.qb   = alloc(NB*NS);
  p.dots = alloc((size_t)NB*NS*NT);
  p.attn = alloc((size_t)NB*NS*NT);
  p.hbar_part = alloc((size_t)NB*8*NS*DD);
  p.Sp_part   = alloc((size_t)NB*8*NS*2);
  p.hbar = alloc(NB*NS*DD);
  p.xnh  = (ushort*)alloc((size_t)NTOT*DIN/2);
  p.xnl  = (ushort*)alloc((size_t)NTOT*DIN/2);
  p.hh   = (ushort*)alloc((size_t)NTOT*DIN/2);
  p.hl   = (ushort*)alloc((size_t)NTOT*DIN/2);
  p.W1Th = (ushort*)alloc((size_t)DIN*DIN/2);
  p.W1Tl = (ushort*)alloc((size_t)DIN*DIN/2);
  p.W2Th = (ushort*)alloc((size_t)DD*DIN/2);
  p.W2Tl = (ushort*)alloc((size_t)DD*DIN/2);
  p.out = (float*)d_out;
  if (ws_size < need*sizeof(float)){
    fprintf(stderr, "kernel_launch: ws too small (%zu < %zu)\n", ws_size, need*sizeof(float));
    return;
  }

  prep_weights<<<dim3(DD), dim3(DD), 0, stream>>>(p);
  transpose_split<<<dim3(DIN/64, DIN/64), dim3(256), 0, stream>>>(p.im_w1, p.W1Th, p.W1Tl, DIN, DIN);
  transpose_split<<<dim3(DIN/64, DD/64), dim3(256), 0, stream>>>(p.im_w2, p.W2Th, p.W2Tl, DIN, DD);
  init_state<<<dim3((NB*NS*DD+255)/256), dim3(256), 0, stream>>>(p);
  gather_ag<<<dim3((NTOT+255)/256), dim3(256), 0, stream>>>(p);
  ln1_split<<<dim3(NTOT/4), dim3(256), 0, stream>>>(p);
  gemm_split<1><<<dim3(DIN/128, (NTOT+63)/64), dim3(256), 0, stream>>>(
      p.xnh, p.xnl, p.W1Th, p.W1Tl, p.im_b1, p.hh, p.hl,
      nullptr, nullptr, nullptr, NTOT);
  gemm_split<2><<<dim3(1, (NTOT+63)/64), dim3(256), 0, stream>>>(
      p.hh, p.hl, p.W2Th, p.W2Tl, p.im_b2, nullptr, nullptr,
      p.x, p.im_ln2_g, p.im_ln2_b, NTOT);
  k2_proj<<<dim3((NTOT+31)/32), dim3(256), 0, stream>>>(p);

  float* Sp[2] = {p.Sp0, p.Sp1};
  float* Ss[2] = {p.Ss0, p.Ss1};
  int cur = 0;
  for (int t = 0; t < 4; t++){
    k3_slots<<<dim3(NB*NS), dim3(128), 0, stream>>>(p);
    k4_dots<<<dim3(NB*7), dim3(256), 0, stream>>>(p, Sp[cur], Ss[cur]);
    k5_softmax<<<dim3(NB), dim3(256), 0, stream>>>(p);
    if (t < 3){
      k6a<<<dim3(NB*8), dim3(256), 0, stream>>>(p, Sp[cur], Ss[cur]);
      k6r<<<dim3(NB*NS), dim3(128), 0, stream>>>(p, Sp[cur^1], Ss[cur^1]);
      k7_update<<<dim3(NB*NS), dim3(128), 0, stream>>>(p);
      cur ^= 1;
    }
  }
  k8_final<<<dim3(NB*NS), dim3(128), 0, stream>>>(p);
  k8_attn<<<dim3((8*NS*NT+255)/256), dim3(256), 0, stream>>>(p);
}